// Round 2
// baseline (136.579 us; speedup 1.0000x reference)
//
#include <hip/hip_runtime.h>
#include <hip/hip_bf16.h>

// MultiStepUnitaryGCN — closed-form collapse:
//   For star adjacency A (center 0, degree d): Re(expm(-itA)[0,0]) = cos(t*sqrt(d)),
//   Re(expm(-itA)[0,j>=1]) = 0 EXACTLY (holds for Pade+scaling-squaring too: the
//   approximant satisfies r(iy)=exp(i*theta(y)), so the even/real part cancels),
//   and smax = 1 (unitary). => conv(h) = cos(t*sqrt(deg)) * (h @ W^T) + b.
//   Neighbors are dead code; only deg = sum(nbr_mask) matters.
// Fused: h = relu(c1*(x@W1^T)+b1); o = c2*(h@W2^T)+b2; out = log_softmax(o).
//
// Dtypes (round-2 fix): reference tensors are float32 -> const float*; mask is
// int32 (bool promoted per harness "integer -> const int*"); output float32.
// Round-1 NaN was f32 buffers misread as bf16 (mantissa halves decode to NaN
// with p~1/256). We now stage f32 -> bf16 into LDS (fits 64KB), accumulate f32.

#define NN    50000
#define CIN   128
#define CHID  128
#define COUT  64
#define KNBR  16
#define TM    48      // nodes per block
#define BLOCK 256

typedef unsigned short u16;
typedef unsigned int   u32;

__device__ __forceinline__ u16 f2bf(float f) {
    __hip_bfloat16 h = __float2bfloat16(f);
    return *reinterpret_cast<u16*>(&h);
}
__device__ __forceinline__ void cvt8(uint4 v, float* f) {
    f[0] = __uint_as_float(v.x << 16);
    f[1] = __uint_as_float(v.x & 0xffff0000u);
    f[2] = __uint_as_float(v.y << 16);
    f[3] = __uint_as_float(v.y & 0xffff0000u);
    f[4] = __uint_as_float(v.z << 16);
    f[5] = __uint_as_float(v.z & 0xffff0000u);
    f[6] = __uint_as_float(v.w << 16);
    f[7] = __uint_as_float(v.w & 0xffff0000u);
}
// pack 8 consecutive f32 (from global) into 8 bf16 (one uint4) for LDS
__device__ __forceinline__ uint4 pack8(const float* __restrict__ p) {
    float tmp[8];
    *(float4*)(tmp)     = *(const float4*)(p);
    *(float4*)(tmp + 4) = *(const float4*)(p + 4);
    union { u16 h[8]; uint4 v; } r;
    #pragma unroll
    for (int i = 0; i < 8; ++i) r.h[i] = f2bf(tmp[i]);
    return r.v;
}

// XOR swizzle: element group g (8 bf16 = 16B) of row r stored at group (g ^ (r&15)).
// Node-strided (16 distinct rows/wave) and channel-strided b128 reads are then
// bank-conflict-free with zero padding.
__device__ __forceinline__ int sw(int row, int g) { return (g ^ (row & 15)) << 3; }

__global__ __launch_bounds__(BLOCK, 2)
void gcn_fused(const float* __restrict__ xg,
               const int* __restrict__ maskg,
               const float* __restrict__ w1g,
               const float* __restrict__ b1g,
               const float* __restrict__ w2g,
               const float* __restrict__ b2g,
               float* __restrict__ out)
{
    // LDS: w1 [128][128] bf16 (32768 B) | w2 [64][128] bf16 (16384 B) | xt/ht [48][128] bf16 (12288 B)
    // osc [48][68] f32 aliases w1 (w1 only read in phase 1).
    __shared__ __align__(16) char lds_raw[32768 + 16384 + 12288];
    u16* w1 = (u16*)lds_raw;
    u16* w2 = (u16*)(lds_raw + 32768);
    u16* xt = (u16*)(lds_raw + 32768 + 16384);   // x tile, then h tile (bf16)
    float* osc = (float*)lds_raw;                 // [48][68] o scratch, aliases w1

    __shared__ float c1v[TM], c2v[TM], b1l[CHID], b2l[COUT];
    __shared__ float pm[TM * 4], ps[TM * 4], lsev[TM];

    const int t  = threadIdx.x;
    const int m0 = blockIdx.x * TM;

    // ---- stage W1 (16384 f32 -> bf16, 8 per chunk) ----
    #pragma unroll
    for (int i = 0; i < 8; ++i) {
        int cj = t + i * BLOCK;
        int row = cj >> 4, g = cj & 15;
        *(uint4*)&w1[row * CIN + sw(row, g)] = pack8(w1g + row * CIN + (g << 3));
    }
    // ---- stage W2 (8192 f32) ----
    #pragma unroll
    for (int i = 0; i < 4; ++i) {
        int cj = t + i * BLOCK;
        int row = cj >> 4, g = cj & 15;
        *(uint4*)&w2[row * CHID + sw(row, g)] = pack8(w2g + row * CHID + (g << 3));
    }
    // ---- stage x tile (48 rows x 128 f32) ----
    #pragma unroll
    for (int i = 0; i < 3; ++i) {
        int cj = t + i * BLOCK;
        int n = cj >> 4, g = cj & 15;
        int gn = m0 + n;
        uint4 v = make_uint4(0u, 0u, 0u, 0u);
        if (gn < NN) v = pack8(xg + (size_t)gn * CIN + (g << 3));
        *(uint4*)&xt[n * CIN + sw(n, g)] = v;
    }
    // ---- biases (f32) ----
    if (t < CHID) b1l[t] = b1g[t];
    if (t < COUT) b2l[t] = b2g[t];
    // ---- degree -> evolution weights c1 = cos(T1*sqrt(d)), c2 = cos(T2*sqrt(d)) ----
    if (t < TM) {
        int gn = m0 + t;
        int deg = 0;
        if (gn < NN) {
            #pragma unroll
            for (int j = 0; j < KNBR; ++j) deg += (maskg[(size_t)gn * KNBR + j] != 0);
        }
        float sd = sqrtf((float)deg);
        c1v[t] = cosf(sd);          // T1 = 1.0
        c2v[t] = cosf(0.5f * sd);   // T2 = 0.5
    }
    __syncthreads();

    // ---- phase 1: h = relu(c1 * (x @ W1^T) + b1), micro-tile 3 nodes x 8 chans ----
    const int nb = t & 15;    // node group: nodes nb + 16i
    const int cb = t >> 4;    // channel group: chans cb + 16j
    float acc[3][8];
    #pragma unroll
    for (int i = 0; i < 3; ++i)
        #pragma unroll
        for (int j = 0; j < 8; ++j) acc[i][j] = 0.f;

    for (int k8 = 0; k8 < CIN / 8; ++k8) {
        float xf[3][8];
        #pragma unroll
        for (int i = 0; i < 3; ++i)
            cvt8(*(const uint4*)&xt[(nb + 16 * i) * CIN + sw(nb, k8)], xf[i]);
        #pragma unroll
        for (int j = 0; j < 8; ++j) {
            int c = cb + 16 * j;
            float wf[8];
            cvt8(*(const uint4*)&w1[c * CIN + sw(c, k8)], wf);
            #pragma unroll
            for (int i = 0; i < 3; ++i)
                #pragma unroll
                for (int q = 0; q < 8; ++q)
                    acc[i][j] = fmaf(xf[i][q], wf[q], acc[i][j]);
        }
    }

    __syncthreads();   // all xt/w1 reads done; safe to overwrite xt with h
    #pragma unroll
    for (int i = 0; i < 3; ++i) {
        int n = nb + 16 * i;
        float c1 = c1v[n];
        #pragma unroll
        for (int j = 0; j < 8; ++j) {
            int c = cb + 16 * j;
            float h = fmaxf(fmaf(c1, acc[i][j], b1l[c]), 0.f);
            xt[n * CIN + sw(n, c >> 3) + (c & 7)] = f2bf(h);
        }
    }
    __syncthreads();

    // ---- phase 2: o = c2 * (h @ W2^T) + b2, micro-tile 3 nodes x 4 chans ----
    float a2[3][4];
    #pragma unroll
    for (int i = 0; i < 3; ++i)
        #pragma unroll
        for (int j = 0; j < 4; ++j) a2[i][j] = 0.f;

    for (int k8 = 0; k8 < CHID / 8; ++k8) {
        float hf[3][8];
        #pragma unroll
        for (int i = 0; i < 3; ++i)
            cvt8(*(const uint4*)&xt[(nb + 16 * i) * CIN + sw(nb, k8)], hf[i]);
        #pragma unroll
        for (int j = 0; j < 4; ++j) {
            int c = cb + 16 * j;
            float wf[8];
            cvt8(*(const uint4*)&w2[c * CHID + sw(c, k8)], wf);
            #pragma unroll
            for (int i = 0; i < 3; ++i)
                #pragma unroll
                for (int q = 0; q < 8; ++q)
                    a2[i][j] = fmaf(hf[i][q], wf[q], a2[i][j]);
        }
    }

    // o -> LDS scratch (aliases w1; w1 reads all completed before earlier barrier)
    #pragma unroll
    for (int i = 0; i < 3; ++i) {
        int n = nb + 16 * i;
        float c2 = c2v[n];
        #pragma unroll
        for (int j = 0; j < 4; ++j) {
            int c = cb + 16 * j;
            osc[n * 68 + c] = fmaf(c2, a2[i][j], b2l[c]);
        }
    }
    __syncthreads();

    // ---- log-softmax over 64 classes: 4 partials per node ----
    {
        int node = t >> 2, part = t & 3;
        if (node < TM) {
            float m = -1e30f;
            #pragma unroll
            for (int q = 0; q < 16; ++q)
                m = fmaxf(m, osc[node * 68 + part * 16 + q]);
            pm[node * 4 + part] = m;
        }
    }
    __syncthreads();
    {
        int node = t >> 2, part = t & 3;
        if (node < TM) {
            float M = fmaxf(fmaxf(pm[node * 4], pm[node * 4 + 1]),
                            fmaxf(pm[node * 4 + 2], pm[node * 4 + 3]));
            float s = 0.f;
            #pragma unroll
            for (int q = 0; q < 16; ++q)
                s += expf(osc[node * 68 + part * 16 + q] - M);
            ps[node * 4 + part] = s;
            if (part == 0) pm[node * 4] = M;   // stash max for lse
        }
    }
    __syncthreads();
    {
        int node = t >> 2, part = t & 3;
        if (node < TM && part == 0) {
            lsev[node] = pm[node * 4] +
                logf(ps[node * 4] + ps[node * 4 + 1] + ps[node * 4 + 2] + ps[node * 4 + 3]);
        }
    }
    __syncthreads();

    // ---- coalesced float4 output: out[n][c] = o - lse ----
    for (int e4 = t; e4 < TM * COUT / 4; e4 += BLOCK) {
        int n = e4 >> 4;               // 16 float4 per node
        if (m0 + n >= NN) break;       // n nondecreasing
        int c0 = (e4 & 15) << 2;
        float l = lsev[n];
        float4 v;
        v.x = osc[n * 68 + c0]     - l;
        v.y = osc[n * 68 + c0 + 1] - l;
        v.z = osc[n * 68 + c0 + 2] - l;
        v.w = osc[n * 68 + c0 + 3] - l;
        *(float4*)(out + (size_t)(m0 + n) * COUT + c0) = v;
    }
}

extern "C" void kernel_launch(void* const* d_in, const int* in_sizes, int n_in,
                              void* d_out, int out_size, void* d_ws, size_t ws_size,
                              hipStream_t stream) {
    const float* x   = (const float*)d_in[0];
    // d_in[1] = neighbors — mathematically irrelevant (Re(G[0,j>=1]) == 0)
    const int* mask  = (const int*)d_in[2];
    const float* w1  = (const float*)d_in[3];
    const float* b1  = (const float*)d_in[4];
    const float* w2  = (const float*)d_in[5];
    const float* b2  = (const float*)d_in[6];
    float* out = (float*)d_out;

    int grid = (NN + TM - 1) / TM;   // 1042
    hipLaunchKernelGGL(gcn_fused, dim3(grid), dim3(BLOCK), 0, stream,
                       x, mask, w1, b1, w2, b2, out);
}

// Round 3
// 102.863 us; speedup vs baseline: 1.3278x; 1.3278x over previous
//
#include <hip/hip_runtime.h>
#include <hip/hip_bf16.h>

// MultiStepUnitaryGCN — closed-form collapse (verified: round-0 ref magnitude
// matches log_softmax scale; round-2 passed with absmax 0.031):
//   conv(h) = cos(t*sqrt(deg)) * (h @ W^T) + b ; neighbors are dead code.
// Round-3: move the two GEMMs onto MFMA (bf16 16x16x32), weights as register
// B-frags, x/h tiles in swizzled LDS. 64 nodes/block, 4 waves:
//   phase1: wave w -> channels [32w,32w+32) x 64 nodes (4Mx2N tiles, 32 MFMA)
//   phase2: wave w -> channels [16w,16w+16) x 64 nodes (4Mx1N tiles, 16 MFMA)
// Fragment layouts per verified m89/m91 mapping:
//   A[m=lane&15][k=(lane>>4)*8+j], B[k][n]: lane holds W[n=lane&15][k contig],
//   C/D: col=lane&15, row=(lane>>4)*4+reg.

#define NN    50000
#define CIN   128
#define CHID  128
#define COUT  64
#define KNBR  16
#define TM    64      // nodes per block
#define BLOCK 256

typedef unsigned short u16;
typedef unsigned int   u32;
typedef __attribute__((ext_vector_type(8))) short bf16x8;
typedef __attribute__((ext_vector_type(4))) float f32x4;

__device__ __forceinline__ u16 f2bf(float f) {
    __hip_bfloat16 h = __float2bfloat16(f);
    return *reinterpret_cast<u16*>(&h);
}
// 8 consecutive f32 (global) -> 8 bf16 packed in a uint4 (for LDS store)
__device__ __forceinline__ uint4 pack8u(const float* __restrict__ p) {
    float tmp[8];
    *(float4*)(tmp)     = *(const float4*)(p);
    *(float4*)(tmp + 4) = *(const float4*)(p + 4);
    union { u16 h[8]; uint4 v; } r;
    #pragma unroll
    for (int i = 0; i < 8; ++i) r.h[i] = f2bf(tmp[i]);
    return r.v;
}
// 8 consecutive f32 (global) -> bf16x8 MFMA fragment (registers)
__device__ __forceinline__ bf16x8 pack8f(const float* __restrict__ p) {
    float tmp[8];
    *(float4*)(tmp)     = *(const float4*)(p);
    *(float4*)(tmp + 4) = *(const float4*)(p + 4);
    union { short s[8]; bf16x8 v; } r;
    #pragma unroll
    for (int i = 0; i < 8; ++i) r.s[i] = (short)f2bf(tmp[i]);
    return r.v;
}

// XOR swizzle on 16B groups: group g of row r stored at (g ^ (r&15)).
// Makes the 16-distinct-row b128 fragment reads bank-conflict-free, no padding.
__device__ __forceinline__ int sw(int row, int g) { return (g ^ (row & 15)) << 3; }

__global__ __launch_bounds__(BLOCK, 3)
void gcn_mfma(const float* __restrict__ xg,
              const int* __restrict__ maskg,
              const float* __restrict__ w1g,
              const float* __restrict__ b1g,
              const float* __restrict__ w2g,
              const float* __restrict__ b2g,
              float* __restrict__ out)
{
    // region: xt [64][128] bf16 (16384 B) then, after phase 1, osc [64][68] f32
    // (17408 B) aliases it. ht lives above the max of the two.
    __shared__ __align__(16) char region[17408 + 16384];
    u16*   xt  = (u16*)region;                 // x tile, swizzled bf16
    float* osc = (float*)region;               // o scratch (aliases xt, phase 2+)
    u16*   ht  = (u16*)(region + 17408);       // h tile, swizzled bf16

    __shared__ float c1v[TM], c2v[TM], b1l[CHID], b2l[COUT];
    __shared__ float pm[TM * 4], ps[TM * 4], lsev[TM];

    const int t  = threadIdx.x;
    const int w  = t >> 6;        // wave id 0..3
    const int L  = t & 63;        // lane
    const int q  = L >> 4;        // quad 0..3
    const int lm = L & 15;
    const int m0 = blockIdx.x * TM;

    // ---- stage x tile: 64 rows x 16 groups of 8 f32 -> bf16 ----
    #pragma unroll
    for (int i = 0; i < 4; ++i) {
        int c = t + i * BLOCK;
        int row = c >> 4, g = c & 15;
        int gn = m0 + row;
        uint4 v = make_uint4(0u, 0u, 0u, 0u);
        if (gn < NN) v = pack8u(xg + (size_t)gn * CIN + (g << 3));
        *(uint4*)&xt[row * CIN + sw(row, g)] = v;
    }

    // ---- W1/W2 B-fragments in registers (weights L2-cached across blocks) ----
    // b_frag[j] = W[n = chan][k = q*8 + j]; contiguous k in row-major W.
    bf16x8 w1f[2][4];   // 2 N-tiles (chans w*32+nt*16+lm), 4 K-frags
    #pragma unroll
    for (int nt = 0; nt < 2; ++nt) {
        int c = w * 32 + nt * 16 + lm;
        #pragma unroll
        for (int k4 = 0; k4 < 4; ++k4)
            w1f[nt][k4] = pack8f(w1g + c * CIN + k4 * 32 + q * 8);
    }
    bf16x8 w2f[4];      // 1 N-tile (chan w*16+lm), 4 K-frags
    {
        int c = w * 16 + lm;
        #pragma unroll
        for (int k4 = 0; k4 < 4; ++k4)
            w2f[k4] = pack8f(w2g + c * CHID + k4 * 32 + q * 8);
    }

    // ---- biases, degree -> c1 = cos(sqrt(d)), c2 = cos(0.5*sqrt(d)) ----
    if (t < CHID) b1l[t] = b1g[t];
    if (t < COUT) b2l[t] = b2g[t];
    if (t < TM) {
        int gn = m0 + t;
        int deg = 0;
        if (gn < NN) {
            #pragma unroll
            for (int j = 0; j < KNBR; ++j) deg += (maskg[(size_t)gn * KNBR + j] != 0);
        }
        float sd = sqrtf((float)deg);
        c1v[t] = cosf(sd);          // T1 = 1.0
        c2v[t] = cosf(0.5f * sd);   // T2 = 0.5
    }
    __syncthreads();

    // ---- phase 1: acc = x @ W1^T  (4 M-tiles x 2 N-tiles) ----
    f32x4 acc[4][2];
    #pragma unroll
    for (int i = 0; i < 4; ++i)
        #pragma unroll
        for (int nt = 0; nt < 2; ++nt)
            acc[i][nt] = (f32x4){0.f, 0.f, 0.f, 0.f};

    #pragma unroll
    for (int k4 = 0; k4 < 4; ++k4) {
        bf16x8 af[4];
        #pragma unroll
        for (int i = 0; i < 4; ++i) {
            int r = i * 16 + lm;
            af[i] = *(const bf16x8*)&xt[r * CIN + sw(r, k4 * 4 + q)];
        }
        #pragma unroll
        for (int i = 0; i < 4; ++i)
            #pragma unroll
            for (int nt = 0; nt < 2; ++nt)
                acc[i][nt] = __builtin_amdgcn_mfma_f32_16x16x32_bf16(
                    af[i], w1f[nt][k4], acc[i][nt], 0, 0, 0);
    }

    // h = relu(c1*acc + b1) -> ht (bf16, swizzled A-layout)
    #pragma unroll
    for (int i = 0; i < 4; ++i) {
        #pragma unroll
        for (int nt = 0; nt < 2; ++nt) {
            int chan = w * 32 + nt * 16 + lm;
            float bb = b1l[chan];
            #pragma unroll
            for (int r = 0; r < 4; ++r) {
                int node = i * 16 + q * 4 + r;
                float h = fmaxf(fmaf(c1v[node], acc[i][nt][r], bb), 0.f);
                ht[node * CHID + sw(node, chan >> 3) + (chan & 7)] = f2bf(h);
            }
        }
    }
    __syncthreads();   // ht complete; xt dead -> osc may alias

    // ---- phase 2: a2 = h @ W2^T  (4 M-tiles x 1 N-tile) ----
    f32x4 a2[4];
    #pragma unroll
    for (int i = 0; i < 4; ++i) a2[i] = (f32x4){0.f, 0.f, 0.f, 0.f};

    #pragma unroll
    for (int k4 = 0; k4 < 4; ++k4) {
        bf16x8 af[4];
        #pragma unroll
        for (int i = 0; i < 4; ++i) {
            int r = i * 16 + lm;
            af[i] = *(const bf16x8*)&ht[r * CHID + sw(r, k4 * 4 + q)];
        }
        #pragma unroll
        for (int i = 0; i < 4; ++i)
            a2[i] = __builtin_amdgcn_mfma_f32_16x16x32_bf16(
                af[i], w2f[k4], a2[i], 0, 0, 0);
    }

    // o = c2*a2 + b2 -> osc f32
    {
        int chan = w * 16 + lm;
        float bb = b2l[chan];
        #pragma unroll
        for (int i = 0; i < 4; ++i)
            #pragma unroll
            for (int r = 0; r < 4; ++r) {
                int node = i * 16 + q * 4 + r;
                osc[node * 68 + chan] = fmaf(c2v[node], a2[i][r], bb);
            }
    }
    __syncthreads();

    // ---- log-softmax over 64 classes: 4 partials of 16 per node ----
    {
        int node = t >> 2, part = t & 3;
        float m = -1e30f;
        #pragma unroll
        for (int qq = 0; qq < 16; ++qq)
            m = fmaxf(m, osc[node * 68 + part * 16 + qq]);
        pm[node * 4 + part] = m;
    }
    __syncthreads();
    {
        int node = t >> 2, part = t & 3;
        float M = fmaxf(fmaxf(pm[node * 4], pm[node * 4 + 1]),
                        fmaxf(pm[node * 4 + 2], pm[node * 4 + 3]));
        float s = 0.f;
        #pragma unroll
        for (int qq = 0; qq < 16; ++qq)
            s += expf(osc[node * 68 + part * 16 + qq] - M);
        ps[node * 4 + part] = s;
        if (part == 0) pm[node * 4] = M;
    }
    __syncthreads();
    {
        int node = t >> 2, part = t & 3;
        if (part == 0)
            lsev[node] = pm[node * 4] +
                logf(ps[node * 4] + ps[node * 4 + 1] + ps[node * 4 + 2] + ps[node * 4 + 3]);
    }
    __syncthreads();

    // ---- coalesced float4 output: out[n][c] = o - lse ----
    #pragma unroll
    for (int e4 = t; e4 < TM * COUT / 4; e4 += BLOCK) {
        int n = e4 >> 4;
        if (m0 + n >= NN) break;       // n nondecreasing
        int c0 = (e4 & 15) << 2;
        float l = lsev[n];
        float4 v;
        v.x = osc[n * 68 + c0]     - l;
        v.y = osc[n * 68 + c0 + 1] - l;
        v.z = osc[n * 68 + c0 + 2] - l;
        v.w = osc[n * 68 + c0 + 3] - l;
        *(float4*)(out + (size_t)(m0 + n) * COUT + c0) = v;
    }
}

extern "C" void kernel_launch(void* const* d_in, const int* in_sizes, int n_in,
                              void* d_out, int out_size, void* d_ws, size_t ws_size,
                              hipStream_t stream) {
    const float* x   = (const float*)d_in[0];
    // d_in[1] = neighbors — mathematically irrelevant (Re(G[0,j>=1]) == 0)
    const int* mask  = (const int*)d_in[2];
    const float* w1  = (const float*)d_in[3];
    const float* b1  = (const float*)d_in[4];
    const float* w2  = (const float*)d_in[5];
    const float* b2  = (const float*)d_in[6];
    float* out = (float*)d_out;

    int grid = (NN + TM - 1) / TM;   // 782
    hipLaunchKernelGGL(gcn_mfma, dim3(grid), dim3(BLOCK), 0, stream,
                       x, mask, w1, b1, w2, b2, out);
}

// Round 4
// 97.160 us; speedup vs baseline: 1.4057x; 1.0587x over previous
//
#include <hip/hip_runtime.h>
#include <hip/hip_bf16.h>

// MultiStepUnitaryGCN — closed-form collapse (validated: absmax 0.031 passing):
//   conv(h) = cos(t*sqrt(deg)) * (h @ W^T) + b ; neighbors are dead code.
// Round-4: hoist weight f32->bf16 frag packing and deg->cos into prep kernels
// (d_ws), so the main kernel loads each MFMA B-frag with a single b128 load.
// Main structure (validated in round 3): 64 nodes/block, 4 waves,
//   phase1: wave w -> chans [32w,32w+32) (4Mx2N, 32 MFMA), h->LDS bf16
//   phase2: wave w -> chans [16w,16w+16) (4Mx1N, 16 MFMA), softmax via LDS.
// Frag layouts (verified): A[m=lane&15][k=(lane>>4)*8+j], B lane holds
// W[n=lane&15][k contiguous 8], C/D col=lane&15, row=(lane>>4)*4+reg.

#define NN    50000
#define CIN   128
#define CHID  128
#define COUT  64
#define KNBR  16
#define TM    64      // nodes per block
#define BLOCK 256

typedef unsigned short u16;
typedef unsigned int   u32;
typedef __attribute__((ext_vector_type(8))) short bf16x8;
typedef __attribute__((ext_vector_type(4))) float f32x4;

__device__ __forceinline__ u16 f2bf(float f) {
    __hip_bfloat16 h = __float2bfloat16(f);
    return *reinterpret_cast<u16*>(&h);
}
// 8 consecutive f32 (global) -> 8 bf16 packed in a uint4
__device__ __forceinline__ uint4 pack8u(const float* __restrict__ p) {
    float tmp[8];
    *(float4*)(tmp)     = *(const float4*)(p);
    *(float4*)(tmp + 4) = *(const float4*)(p + 4);
    union { u16 h[8]; uint4 v; } r;
    #pragma unroll
    for (int i = 0; i < 8; ++i) r.h[i] = f2bf(tmp[i]);
    return r.v;
}

// XOR swizzle on 16B groups: group g of row r stored at (g ^ (r&15)).
__device__ __forceinline__ int sw(int row, int g) { return (g ^ (row & 15)) << 3; }

// d_ws layout:
//   [0, 48K): weight frag image, uint4 groups of 8 bf16.
//     W1 group (c,kg) -> index kg*128 + c        (c in [0,128), kg = k/8 in [0,16))
//     W2 group (c,kg) -> index 2048 + kg*64 + c  (c in [0,64))
//   [64K, 64K+400000): c1[50000] f32 then c2[50000] f32.
#define WS_CC_OFF 65536

// ---- prep 1: pack W1/W2 into bf16 fragment image ----
__global__ void wprep(const float* __restrict__ w1g,
                      const float* __restrict__ w2g,
                      uint4* __restrict__ wimg)
{
    int gid = blockIdx.x * BLOCK + threadIdx.x;   // 3072 groups total
    if (gid < 2048) {                 // W1: 128 c x 16 kg
        int c = gid >> 4, kg = gid & 15;
        wimg[kg * 128 + c] = pack8u(w1g + c * CIN + kg * 8);
    } else if (gid < 3072) {          // W2: 64 c x 16 kg
        int g2 = gid - 2048;
        int c = g2 >> 4, kg = g2 & 15;
        wimg[2048 + kg * 64 + c] = pack8u(w2g + c * CHID + kg * 8);
    }
}

// ---- prep 2: deg -> c1 = cos(sqrt(d)), c2 = cos(0.5*sqrt(d)) ----
__global__ void cprep(const int* __restrict__ maskg, float* __restrict__ cc)
{
    int n = blockIdx.x * BLOCK + threadIdx.x;
    if (n < NN) {
        int deg = 0;
        #pragma unroll
        for (int j = 0; j < KNBR; ++j) deg += (maskg[(size_t)n * KNBR + j] != 0);
        float sd = sqrtf((float)deg);
        cc[n]      = cosf(sd);          // T1 = 1.0
        cc[NN + n] = cosf(0.5f * sd);   // T2 = 0.5
    }
}

__global__ __launch_bounds__(BLOCK, 3)
void gcn_mfma(const float* __restrict__ xg,
              const uint4* __restrict__ wimg,
              const float* __restrict__ cc,
              const float* __restrict__ b1g,
              const float* __restrict__ b2g,
              float* __restrict__ out)
{
    // region: xt [64][128] bf16 (16384 B); after phase 1, osc [64][68] f32
    // (17408 B) aliases it. ht lives above the max of the two.
    __shared__ __align__(16) char region[17408 + 16384];
    u16*   xt  = (u16*)region;                 // x tile, swizzled bf16
    float* osc = (float*)region;               // o scratch (aliases xt)
    u16*   ht  = (u16*)(region + 17408);       // h tile, swizzled bf16

    __shared__ float c1v[TM], c2v[TM], b1l[CHID], b2l[COUT];
    __shared__ float pm[TM * 4], ps[TM * 4], lsev[TM];

    const int t  = threadIdx.x;
    const int w  = t >> 6;        // wave id 0..3
    const int L  = t & 63;        // lane
    const int q  = L >> 4;        // quad 0..3
    const int lm = L & 15;
    const int m0 = blockIdx.x * TM;

    // ---- stage x tile: 64 rows x 16 groups of 8 f32 -> bf16 ----
    #pragma unroll
    for (int i = 0; i < 4; ++i) {
        int c = t + i * BLOCK;
        int row = c >> 4, g = c & 15;
        int gn = m0 + row;
        uint4 v = make_uint4(0u, 0u, 0u, 0u);
        if (gn < NN) v = pack8u(xg + (size_t)gn * CIN + (g << 3));
        *(uint4*)&xt[row * CIN + sw(row, g)] = v;
    }

    // ---- W1 B-frags: single b128 loads from pre-packed image ----
    bf16x8 w1f[2][4];
    #pragma unroll
    for (int nt = 0; nt < 2; ++nt) {
        int c = w * 32 + nt * 16 + lm;
        #pragma unroll
        for (int k4 = 0; k4 < 4; ++k4)
            w1f[nt][k4] = *(const bf16x8*)&wimg[(k4 * 4 + q) * 128 + c];
    }

    // ---- biases + precomputed c1/c2 ----
    if (t < CHID) b1l[t] = b1g[t];
    if (t < COUT) b2l[t] = b2g[t];
    if (t < TM) {
        int gn = m0 + t;
        c1v[t] = (gn < NN) ? cc[gn]      : 0.f;
        c2v[t] = (gn < NN) ? cc[NN + gn] : 0.f;
    }
    __syncthreads();

    // ---- phase 1: acc = x @ W1^T  (4 M-tiles x 2 N-tiles) ----
    f32x4 acc[4][2];
    #pragma unroll
    for (int i = 0; i < 4; ++i)
        #pragma unroll
        for (int nt = 0; nt < 2; ++nt)
            acc[i][nt] = (f32x4){0.f, 0.f, 0.f, 0.f};

    #pragma unroll
    for (int k4 = 0; k4 < 4; ++k4) {
        bf16x8 af[4];
        #pragma unroll
        for (int i = 0; i < 4; ++i) {
            int r = i * 16 + lm;
            af[i] = *(const bf16x8*)&xt[r * CIN + sw(r, k4 * 4 + q)];
        }
        #pragma unroll
        for (int i = 0; i < 4; ++i)
            #pragma unroll
            for (int nt = 0; nt < 2; ++nt)
                acc[i][nt] = __builtin_amdgcn_mfma_f32_16x16x32_bf16(
                    af[i], w1f[nt][k4], acc[i][nt], 0, 0, 0);
    }

    // h = relu(c1*acc + b1) -> ht (bf16, swizzled A-layout)
    #pragma unroll
    for (int i = 0; i < 4; ++i) {
        #pragma unroll
        for (int nt = 0; nt < 2; ++nt) {
            int chan = w * 32 + nt * 16 + lm;
            float bb = b1l[chan];
            #pragma unroll
            for (int r = 0; r < 4; ++r) {
                int node = i * 16 + q * 4 + r;
                float h = fmaxf(fmaf(c1v[node], acc[i][nt][r], bb), 0.f);
                ht[node * CHID + sw(node, chan >> 3) + (chan & 7)] = f2bf(h);
            }
        }
    }

    // ---- W2 B-frags (loaded late: short live range) ----
    bf16x8 w2f[4];
    {
        int c = w * 16 + lm;
        #pragma unroll
        for (int k4 = 0; k4 < 4; ++k4)
            w2f[k4] = *(const bf16x8*)&wimg[2048 + (k4 * 4 + q) * 64 + c];
    }
    __syncthreads();   // ht complete; xt dead -> osc may alias

    // ---- phase 2: a2 = h @ W2^T  (4 M-tiles x 1 N-tile) ----
    f32x4 a2[4];
    #pragma unroll
    for (int i = 0; i < 4; ++i) a2[i] = (f32x4){0.f, 0.f, 0.f, 0.f};

    #pragma unroll
    for (int k4 = 0; k4 < 4; ++k4) {
        bf16x8 af[4];
        #pragma unroll
        for (int i = 0; i < 4; ++i) {
            int r = i * 16 + lm;
            af[i] = *(const bf16x8*)&ht[r * CHID + sw(r, k4 * 4 + q)];
        }
        #pragma unroll
        for (int i = 0; i < 4; ++i)
            a2[i] = __builtin_amdgcn_mfma_f32_16x16x32_bf16(
                af[i], w2f[k4], a2[i], 0, 0, 0);
    }

    // o = c2*a2 + b2 -> osc f32
    {
        int chan = w * 16 + lm;
        float bb = b2l[chan];
        #pragma unroll
        for (int i = 0; i < 4; ++i)
            #pragma unroll
            for (int r = 0; r < 4; ++r) {
                int node = i * 16 + q * 4 + r;
                osc[node * 68 + chan] = fmaf(c2v[node], a2[i][r], bb);
            }
    }
    __syncthreads();

    // ---- log-softmax over 64 classes: 4 partials of 16 per node ----
    {
        int node = t >> 2, part = t & 3;
        float m = -1e30f;
        #pragma unroll
        for (int qq = 0; qq < 16; ++qq)
            m = fmaxf(m, osc[node * 68 + part * 16 + qq]);
        pm[node * 4 + part] = m;
    }
    __syncthreads();
    {
        int node = t >> 2, part = t & 3;
        float M = fmaxf(fmaxf(pm[node * 4], pm[node * 4 + 1]),
                        fmaxf(pm[node * 4 + 2], pm[node * 4 + 3]));
        float s = 0.f;
        #pragma unroll
        for (int qq = 0; qq < 16; ++qq)
            s += expf(osc[node * 68 + part * 16 + qq] - M);
        ps[node * 4 + part] = s;
        if (part == 0) pm[node * 4] = M;
    }
    __syncthreads();
    {
        int node = t >> 2, part = t & 3;
        if (part == 0)
            lsev[node] = pm[node * 4] +
                logf(ps[node * 4] + ps[node * 4 + 1] + ps[node * 4 + 2] + ps[node * 4 + 3]);
    }
    __syncthreads();

    // ---- coalesced float4 output: out[n][c] = o - lse ----
    for (int e4 = t; e4 < TM * COUT / 4; e4 += BLOCK) {
        int n = e4 >> 4;
        if (m0 + n >= NN) break;       // n nondecreasing per thread
        int c0 = (e4 & 15) << 2;
        float l = lsev[n];
        float4 v;
        v.x = osc[n * 68 + c0]     - l;
        v.y = osc[n * 68 + c0 + 1] - l;
        v.z = osc[n * 68 + c0 + 2] - l;
        v.w = osc[n * 68 + c0 + 3] - l;
        *(float4*)(out + (size_t)(m0 + n) * COUT + c0) = v;
    }
}

extern "C" void kernel_launch(void* const* d_in, const int* in_sizes, int n_in,
                              void* d_out, int out_size, void* d_ws, size_t ws_size,
                              hipStream_t stream) {
    const float* x   = (const float*)d_in[0];
    // d_in[1] = neighbors — mathematically irrelevant (Re(G[0,j>=1]) == 0)
    const int* mask  = (const int*)d_in[2];
    const float* w1  = (const float*)d_in[3];
    const float* b1  = (const float*)d_in[4];
    const float* w2  = (const float*)d_in[5];
    const float* b2  = (const float*)d_in[6];
    float* out = (float*)d_out;

    uint4* wimg = (uint4*)d_ws;
    float* cc   = (float*)((char*)d_ws + WS_CC_OFF);

    hipLaunchKernelGGL(wprep, dim3(12), dim3(BLOCK), 0, stream, w1, w2, wimg);
    hipLaunchKernelGGL(cprep, dim3((NN + BLOCK - 1) / BLOCK), dim3(BLOCK), 0, stream,
                       mask, cc);

    int grid = (NN + TM - 1) / TM;   // 782
    hipLaunchKernelGGL(gcn_mfma, dim3(grid), dim3(BLOCK), 0, stream,
                       x, wimg, cc, b1, b2, out);
}

// Round 5
// 92.093 us; speedup vs baseline: 1.4831x; 1.0550x over previous
//
#include <hip/hip_runtime.h>
#include <hip/hip_bf16.h>

// MultiStepUnitaryGCN — closed-form collapse (validated rounds 2-4, absmax 0.031):
//   conv(h) = cos(t*sqrt(deg)) * (h @ W^T) + b ; neighbors are dead code.
// Round-5: swapped MFMA operand roles -> C[chan][node]. A=W frags (same wimg
// image), B=x/h frags (same swizzled LDS layout). Wins:
//   - phase-1 h-write: reg quad r = 4 consecutive chans -> 8x ds_write_b64
//     (was 32x ds_write_u16), 2-way bank aliasing only (free).
//   - phase-2: wave w owns nodes [16w,16w+16) with ALL 64 chans in lane/quad
//     regs -> softmax = in-reg + 2 shfl_xor(16,32); no osc LDS, no syncs.
//   - 2 syncthreads total; LDS 32 KB; epilogue = float4 reg stores.
//   - wprep+cprep fused (one less launch); biases/cc read direct (L2-hot).
// Frag layout (verified m89/m91): A[m=lane&15][k=(lane>>4)*8+j], B[k][n=lane&15]
// same shape; C/D: row m=(lane>>4)*4+reg, col n=lane&15.

#define NN    50000
#define CIN   128
#define CHID  128
#define COUT  64
#define KNBR  16
#define TM    64      // nodes per block
#define BLOCK 256

typedef unsigned short u16;
typedef unsigned int   u32;
typedef __attribute__((ext_vector_type(8))) short bf16x8;
typedef __attribute__((ext_vector_type(4))) float f32x4;

__device__ __forceinline__ u16 f2bf(float f) {
    __hip_bfloat16 h = __float2bfloat16(f);
    return *reinterpret_cast<u16*>(&h);
}
__device__ __forceinline__ uint4 pack8u(const float* __restrict__ p) {
    float tmp[8];
    *(float4*)(tmp)     = *(const float4*)(p);
    *(float4*)(tmp + 4) = *(const float4*)(p + 4);
    union { u16 h[8]; uint4 v; } r;
    #pragma unroll
    for (int i = 0; i < 8; ++i) r.h[i] = f2bf(tmp[i]);
    return r.v;
}

// XOR swizzle on 16B groups: group g of row r stored at (g ^ (r&15)).
__device__ __forceinline__ int sw(int row, int g) { return (g ^ (row & 15)) << 3; }

// d_ws layout:
//   [0, 48K): weight frag image (uint4 = 8 bf16):
//     W1 group (c,kg) -> idx kg*128 + c         (c<128, kg=k/8<16)
//     W2 group (c,kg) -> idx 2048 + kg*64 + c   (c<64)
//   [64K, ...): c1[50000] f32, c2[50000] f32.
#define WS_CC_OFF 65536
#define CC_BLOCKS 196   // ceil(50000/256)

// ---- fused prep: blocks [0,196) -> deg->cos ; blocks [196,208) -> W pack ----
__global__ void prep(const float* __restrict__ w1g,
                     const float* __restrict__ w2g,
                     const int* __restrict__ maskg,
                     uint4* __restrict__ wimg,
                     float* __restrict__ cc)
{
    int b = blockIdx.x;
    if (b < CC_BLOCKS) {
        int n = b * BLOCK + threadIdx.x;
        if (n < NN) {
            int deg = 0;
            #pragma unroll
            for (int j = 0; j < KNBR; ++j) deg += (maskg[(size_t)n * KNBR + j] != 0);
            float sd = sqrtf((float)deg);
            cc[n]      = cosf(sd);          // T1 = 1.0
            cc[NN + n] = cosf(0.5f * sd);   // T2 = 0.5
        }
    } else {
        int gid = (b - CC_BLOCKS) * BLOCK + threadIdx.x;   // 0..3071
        if (gid < 2048) {                 // W1: 128 c x 16 kg
            int c = gid >> 4, kg = gid & 15;
            wimg[kg * 128 + c] = pack8u(w1g + c * CIN + kg * 8);
        } else if (gid < 3072) {          // W2: 64 c x 16 kg
            int g2 = gid - 2048;
            int c = g2 >> 4, kg = g2 & 15;
            wimg[2048 + kg * 64 + c] = pack8u(w2g + c * CHID + kg * 8);
        }
    }
}

__global__ __launch_bounds__(BLOCK, 3)
void gcn_mfma(const float* __restrict__ xg,
              const uint4* __restrict__ wimg,
              const float* __restrict__ cc,
              const float* __restrict__ b1g,
              const float* __restrict__ b2g,
              float* __restrict__ out)
{
    __shared__ __align__(16) u16 xt[TM * CIN];    // 16 KB, swizzled bf16
    __shared__ __align__(16) u16 ht[TM * CHID];   // 16 KB, swizzled bf16

    const int t  = threadIdx.x;
    const int w  = t >> 6;        // wave 0..3
    const int L  = t & 63;
    const int q  = L >> 4;        // quad 0..3
    const int lm = L & 15;
    const int m0 = blockIdx.x * TM;

    // ---- stage x tile: 64 rows x 16 groups (8 f32 -> 8 bf16) ----
    #pragma unroll
    for (int i = 0; i < 4; ++i) {
        int c = t + i * BLOCK;
        int row = c >> 4, g = c & 15;
        int gn = m0 + row;
        uint4 v = make_uint4(0u, 0u, 0u, 0u);
        if (gn < NN) v = pack8u(xg + (size_t)gn * CIN + (g << 3));
        *(uint4*)&xt[row * CIN + sw(row, g)] = v;
    }

    // ---- W1 A-frags: chans (2w+mt)*16+lm, k-chunk kg=k4*4+q ----
    bf16x8 w1f[2][4];
    #pragma unroll
    for (int mt = 0; mt < 2; ++mt) {
        int c = (2 * w + mt) * 16 + lm;
        #pragma unroll
        for (int k4 = 0; k4 < 4; ++k4)
            w1f[mt][k4] = *(const bf16x8*)&wimg[(k4 * 4 + q) * 128 + c];
    }
    // c1 per N-tile node (direct global, L2-hot)
    float c1n[4];
    #pragma unroll
    for (int nt = 0; nt < 4; ++nt) {
        int gn = m0 + nt * 16 + lm;
        c1n[nt] = (gn < NN) ? cc[gn] : 0.f;
    }
    __syncthreads();

    // ---- phase 1: C1[chan][node] = W1 * x^T  (2 M-tiles x 4 N-tiles) ----
    f32x4 acc[2][4];
    #pragma unroll
    for (int mt = 0; mt < 2; ++mt)
        #pragma unroll
        for (int nt = 0; nt < 4; ++nt)
            acc[mt][nt] = (f32x4){0.f, 0.f, 0.f, 0.f};

    #pragma unroll
    for (int k4 = 0; k4 < 4; ++k4) {
        bf16x8 xf[4];
        #pragma unroll
        for (int nt = 0; nt < 4; ++nt) {
            int r = nt * 16 + lm;
            xf[nt] = *(const bf16x8*)&xt[r * CIN + sw(r, k4 * 4 + q)];
        }
        #pragma unroll
        for (int mt = 0; mt < 2; ++mt)
            #pragma unroll
            for (int nt = 0; nt < 4; ++nt)
                acc[mt][nt] = __builtin_amdgcn_mfma_f32_16x16x32_bf16(
                    w1f[mt][k4], xf[nt], acc[mt][nt], 0, 0, 0);
    }

    // h = relu(c1*acc + b1): reg quad = 4 consecutive chans -> one b64 per tile
    #pragma unroll
    for (int mt = 0; mt < 2; ++mt) {
        int chan0 = (2 * w + mt) * 16 + q * 4;
        float4 bb = *(const float4*)(b1g + chan0);
        #pragma unroll
        for (int nt = 0; nt < 4; ++nt) {
            int node = nt * 16 + lm;
            float c1 = c1n[nt];
            u16 h0 = f2bf(fmaxf(fmaf(c1, acc[mt][nt][0], bb.x), 0.f));
            u16 h1 = f2bf(fmaxf(fmaf(c1, acc[mt][nt][1], bb.y), 0.f));
            u16 h2 = f2bf(fmaxf(fmaf(c1, acc[mt][nt][2], bb.z), 0.f));
            u16 h3 = f2bf(fmaxf(fmaf(c1, acc[mt][nt][3], bb.w), 0.f));
            uint2 pkt = make_uint2(((u32)h0) | ((u32)h1 << 16),
                                   ((u32)h2) | ((u32)h3 << 16));
            *(uint2*)&ht[node * CHID + sw(node, chan0 >> 3) + (chan0 & 7)] = pkt;
        }
    }
    __syncthreads();

    // ---- phase 2: wave w owns nodes [16w,16w+16); all 4 chan M-tiles ----
    const int node = 16 * w + lm;
    const int gn   = m0 + node;

    bf16x8 hf[4];
    #pragma unroll
    for (int k4 = 0; k4 < 4; ++k4)
        hf[k4] = *(const bf16x8*)&ht[node * CHID + sw(node, k4 * 4 + q)];

    float o[4][4];   // [mt][r]: chan = mt*16 + q*4 + r, this lane's node
    float c2 = (gn < NN) ? cc[NN + gn] : 0.f;
    #pragma unroll
    for (int mt = 0; mt < 4; ++mt) {
        bf16x8 w2f[4];
        #pragma unroll
        for (int k4 = 0; k4 < 4; ++k4)
            w2f[k4] = *(const bf16x8*)&wimg[2048 + (k4 * 4 + q) * 64 + (mt * 16 + lm)];
        f32x4 a2 = (f32x4){0.f, 0.f, 0.f, 0.f};
        #pragma unroll
        for (int k4 = 0; k4 < 4; ++k4)
            a2 = __builtin_amdgcn_mfma_f32_16x16x32_bf16(w2f[k4], hf[k4], a2, 0, 0, 0);
        float4 bb = *(const float4*)(b2g + mt * 16 + q * 4);
        o[mt][0] = fmaf(c2, a2[0], bb.x);
        o[mt][1] = fmaf(c2, a2[1], bb.y);
        o[mt][2] = fmaf(c2, a2[2], bb.z);
        o[mt][3] = fmaf(c2, a2[3], bb.w);
    }

    // ---- in-register log-softmax over 64 chans (16 in-lane x 4 quads) ----
    float M = -1e30f;
    #pragma unroll
    for (int mt = 0; mt < 4; ++mt)
        #pragma unroll
        for (int r = 0; r < 4; ++r) M = fmaxf(M, o[mt][r]);
    M = fmaxf(M, __shfl_xor(M, 16));
    M = fmaxf(M, __shfl_xor(M, 32));

    float S = 0.f;
    #pragma unroll
    for (int mt = 0; mt < 4; ++mt)
        #pragma unroll
        for (int r = 0; r < 4; ++r) S += __expf(o[mt][r] - M);
    S += __shfl_xor(S, 16);
    S += __shfl_xor(S, 32);
    float lse = M + __logf(S);

    if (gn < NN) {
        #pragma unroll
        for (int mt = 0; mt < 4; ++mt) {
            float4 v;
            v.x = o[mt][0] - lse;
            v.y = o[mt][1] - lse;
            v.z = o[mt][2] - lse;
            v.w = o[mt][3] - lse;
            *(float4*)(out + (size_t)gn * COUT + mt * 16 + q * 4) = v;
        }
    }
}

extern "C" void kernel_launch(void* const* d_in, const int* in_sizes, int n_in,
                              void* d_out, int out_size, void* d_ws, size_t ws_size,
                              hipStream_t stream) {
    const float* x   = (const float*)d_in[0];
    // d_in[1] = neighbors — mathematically irrelevant (Re(G[0,j>=1]) == 0)
    const int* mask  = (const int*)d_in[2];
    const float* w1  = (const float*)d_in[3];
    const float* b1  = (const float*)d_in[4];
    const float* w2  = (const float*)d_in[5];
    const float* b2  = (const float*)d_in[6];
    float* out = (float*)d_out;

    uint4* wimg = (uint4*)d_ws;
    float* cc   = (float*)((char*)d_ws + WS_CC_OFF);

    hipLaunchKernelGGL(prep, dim3(CC_BLOCKS + 12), dim3(BLOCK), 0, stream,
                       w1, w2, mask, wimg, cc);

    int grid = (NN + TM - 1) / TM;   // 782
    hipLaunchKernelGGL(gcn_mfma, dim3(grid), dim3(BLOCK), 0, stream,
                       x, wimg, cc, b1, b2, out);
}